// Round 1
// baseline (820.935 us; speedup 1.0000x reference)
//
#include <hip/hip_runtime.h>

#define DIM   256
#define KSEQ  2048
#define BATCH 256
#define NROWS (KSEQ * BATCH)      // 524288 flattened (k,b) rows
#define NSTRIPS (NROWS / 32)      // 16384 strips of 32 rows

typedef __attribute__((ext_vector_type(8))) __bf16 bf16x8;
typedef __attribute__((ext_vector_type(4))) float  floatx4;
typedef __attribute__((ext_vector_type(8))) short  short8;

__device__ __forceinline__ unsigned short f2bf_bits(float f) {
    unsigned u = __builtin_bit_cast(unsigned, f);
    u += 0x7fffu + ((u >> 16) & 1u);          // round-to-nearest-even
    return (unsigned short)(u >> 16);
}

__device__ __forceinline__ __bf16 f2bf(float f) {
    return __builtin_bit_cast(__bf16, f2bf_bits(f));
}

__device__ __forceinline__ float fast_tanh(float x) {
    // tanh(x) = 1 - 2/(e^{2x}+1); v_exp + v_rcp. Saturates correctly at +-inf.
    float e = __expf(2.0f * x);
    return 1.0f - 2.0f * __builtin_amdgcn_rcpf(e + 1.0f);
}

// Kernel 1: qpb[b,d] = sum_e query[b,e]*Wq[d,e] + bq[d] + bref[d]
__global__ void qpb_kernel(const float* __restrict__ query,
                           const float* __restrict__ Wq,
                           const float* __restrict__ bq,
                           const float* __restrict__ bref,
                           float* __restrict__ qpb) {
    __shared__ float qs[DIM];
    const int b = blockIdx.x;
    const int d = threadIdx.x;
    qs[d] = query[b * DIM + d];
    __syncthreads();
    const float* wrow = Wq + d * DIM;
    float acc = 0.f;
#pragma unroll 8
    for (int e = 0; e < DIM; ++e) acc += qs[e] * wrow[e];
    qpb[b * DIM + d] = acc + bq[d] + bref[d];
}

// Kernel 2: fused ref-GEMM + tanh-dot + logit clip.
// Persistent: 256 blocks x 1024 threads (16 waves). Wref bf16 in 128KB LDS.
__global__ __launch_bounds__(1024) void attn_kernel(
        const float* __restrict__ enc,    // (NROWS, DIM) fp32
        const float* __restrict__ qpb,    // (BATCH, DIM) fp32 = q + bref
        const float* __restrict__ Wref,   // (DIM, DIM) fp32
        const float* __restrict__ v,      // (DIM,)
        float* __restrict__ out) {        // (BATCH, KSEQ)
    __shared__ short wlds[DIM * DIM];     // 128 KiB bf16 Wref, xor-swizzled 16B chunks

    const int tid = threadIdx.x;

    // ---- Stage Wref -> LDS as bf16. Chunk = 8 bf16 (16B). 32 chunks/row.
    // Chunk c of row d stored at chunk (c ^ (d & 15)) -> 2-way banks on read.
#pragma unroll
    for (int it = 0; it < 8; ++it) {
        const int flat = it * 1024 + tid;     // 8192 chunks total
        const int d = flat >> 5;
        const int c = flat & 31;
        const float* src = Wref + d * DIM + c * 8;
        float4 f0 = *(const float4*)(src);
        float4 f1 = *(const float4*)(src + 4);
        short8 sv;
        sv[0] = (short)f2bf_bits(f0.x); sv[1] = (short)f2bf_bits(f0.y);
        sv[2] = (short)f2bf_bits(f0.z); sv[3] = (short)f2bf_bits(f0.w);
        sv[4] = (short)f2bf_bits(f1.x); sv[5] = (short)f2bf_bits(f1.y);
        sv[6] = (short)f2bf_bits(f1.z); sv[7] = (short)f2bf_bits(f1.w);
        *(short8*)&wlds[d * DIM + ((c ^ (d & 15)) << 3)] = sv;
    }
    __syncthreads();

    const int lane = tid & 63;
    const int wave = tid >> 6;
    const int n = lane & 15;     // MFMA A-row / B-col / C-col index
    const int g = lane >> 4;     // quad group: k-offset group, C row group

    // Grid-stride over 32-row strips; 4096 waves total -> 4 strips each.
    for (int strip = blockIdx.x * 16 + wave; strip < NSTRIPS; strip += 256 * 16) {
        const int rowbase = strip * 32;

        // ---- Load A fragments for full K=256, 2 M-tiles (32 rows), to regs.
        // A layout for mfma_f32_16x16x32_bf16: lane holds A[m=lane&15][k=g*8+j]
        bf16x8 afrag[2][8];
#pragma unroll
        for (int m = 0; m < 2; ++m) {
            const float* rowp = enc + (size_t)(rowbase + m * 16 + n) * DIM + g * 8;
#pragma unroll
            for (int s = 0; s < 8; ++s) {
                float4 f0 = *(const float4*)(rowp + s * 32);
                float4 f1 = *(const float4*)(rowp + s * 32 + 4);
                bf16x8 a;
                a[0] = f2bf(f0.x); a[1] = f2bf(f0.y); a[2] = f2bf(f0.z); a[3] = f2bf(f0.w);
                a[4] = f2bf(f1.x); a[5] = f2bf(f1.y); a[6] = f2bf(f1.z); a[7] = f2bf(f1.w);
                afrag[m][s] = a;
            }
        }

        float u[2][4] = {{0.f, 0.f, 0.f, 0.f}, {0.f, 0.f, 0.f, 0.f}};
        const int bbase = rowbase & 255;              // rowbase % BATCH (32-aligned)
        const float* qbase = qpb + (size_t)bbase * DIM;

        // ---- 16 n-tiles of d; full e-reduction per tile, then fused epilogue.
        for (int t = 0; t < 16; ++t) {
            const int d = t * 16 + n;
            floatx4 acc0 = {0.f, 0.f, 0.f, 0.f};
            floatx4 acc1 = {0.f, 0.f, 0.f, 0.f};
#pragma unroll
            for (int s = 0; s < 8; ++s) {
                // B layout: lane holds B[k=g*8+j][n] = Wref[d=t*16+n][e=s*32+g*8+j]
                short8 raw = *(const short8*)&wlds[(t * 16 + n) * DIM +
                                                   (((s * 4 + g) ^ n) << 3)];
                bf16x8 bfrag = __builtin_bit_cast(bf16x8, raw);
                acc0 = __builtin_amdgcn_mfma_f32_16x16x32_bf16(afrag[0][s], bfrag, acc0, 0, 0, 0);
                acc1 = __builtin_amdgcn_mfma_f32_16x16x32_bf16(afrag[1][s], bfrag, acc1, 0, 0, 0);
            }
            const float vd = v[d];
            // C/D layout: col = lane&15 (=d residue), row = g*4 + reg
#pragma unroll
            for (int rg = 0; rg < 4; ++rg) {
                const int r0 = (g * 4 + rg) * DIM;
                const int r1 = (16 + g * 4 + rg) * DIM;
                float x0 = acc0[rg] + qbase[r0 + d];
                float x1 = acc1[rg] + qbase[r1 + d];
                u[0][rg] += vd * fast_tanh(x0);
                u[1][rg] += vd * fast_tanh(x1);
            }
        }

        // ---- Reduce u over the 16 lanes of each quad-group, store logits.
#pragma unroll
        for (int m = 0; m < 2; ++m) {
#pragma unroll
            for (int rg = 0; rg < 4; ++rg) {
                float s = u[m][rg];
                s += __shfl_xor(s, 1);
                s += __shfl_xor(s, 2);
                s += __shfl_xor(s, 4);
                s += __shfl_xor(s, 8);
                if (n == 0) {
                    const int r = rowbase + m * 16 + g * 4 + rg;  // r = k*BATCH + b
                    out[(size_t)(r & 255) * KSEQ + (r >> 8)] = 10.0f * fast_tanh(s);
                }
            }
        }
    }
}

extern "C" void kernel_launch(void* const* d_in, const int* in_sizes, int n_in,
                              void* d_out, int out_size, void* d_ws, size_t ws_size,
                              hipStream_t stream) {
    const float* enc   = (const float*)d_in[0];
    const float* query = (const float*)d_in[1];
    const float* Wq    = (const float*)d_in[2];
    const float* bq    = (const float*)d_in[3];
    const float* Wref  = (const float*)d_in[4];
    const float* bref  = (const float*)d_in[5];
    const float* v     = (const float*)d_in[6];
    float* out = (float*)d_out;
    float* qpb = (float*)d_ws;   // 256*256*4 = 256 KiB scratch

    qpb_kernel<<<BATCH, DIM, 0, stream>>>(query, Wq, bq, bref, qpb);
    attn_kernel<<<256, 1024, 0, stream>>>(enc, qpb, Wref, v, out);
}